// Round 1
// baseline (449.163 us; speedup 1.0000x reference)
//
#include <hip/hip_runtime.h>
#include <math.h>

#define N_NODES 50000
#define D       64
#define N_EDGES 800000
#define N_HEAD  4

// ---------------------------------------------------------------------------
// row_ptr[r] = lower_bound(edge_row, r)  for r in [0, N_NODES], edge_row sorted
// ---------------------------------------------------------------------------
__global__ void rowptr_kernel(const int* __restrict__ edge_row,
                              int* __restrict__ row_ptr) {
    int r = blockIdx.x * blockDim.x + threadIdx.x;
    if (r > N_NODES) return;
    int lo = 0, hi = N_EDGES;
    while (lo < hi) {
        int mid = (lo + hi) >> 1;
        if (edge_row[mid] < r) lo = mid + 1; else hi = mid;
    }
    row_ptr[r] = lo;
}

// ---------------------------------------------------------------------------
// t[n][j] = elu( sum_k in[n][k] * W[j][k] + b[j] )
// Optional mask from event_type (head 0 only): in-row zeroed if et[n]==0.
// W staged transposed in LDS with stride 65 (bank-conflict-free reads).
// ---------------------------------------------------------------------------
#define L_ROWS 32
__global__ __launch_bounds__(256) void linear_elu_kernel(
        const float* __restrict__ in,
        const float* __restrict__ W,   // [64][64] row-major, W[j][k]
        const float* __restrict__ b,   // [64]
        const int*  __restrict__ et,   // nullable; mask if et[n]==0
        float* __restrict__ t) {
    __shared__ float Wt[D * 65];       // Wt[k*65+j] = W[j][k]
    __shared__ float rows[L_ROWS][D];

    const int tid = threadIdx.x;
    for (int idx = tid; idx < D * D; idx += 256) {
        int j = idx >> 6, k = idx & 63;
        Wt[k * 65 + j] = W[idx];
    }
    const int rbase = blockIdx.x * L_ROWS;
    for (int idx = tid; idx < L_ROWS * D; idx += 256) {
        int r = idx >> 6, k = idx & 63;
        int gr = rbase + r;
        float v = 0.f;
        if (gr < N_NODES) {
            v = in[gr * D + k];
            if (et && et[gr] == 0) v = 0.f;
        }
        rows[r][k] = v;
    }
    __syncthreads();

    const int j  = tid & 63;
    const float bj = b[j];
    for (int r = tid >> 6; r < L_ROWS; r += 4) {
        int gr = rbase + r;
        if (gr >= N_NODES) continue;
        float acc = bj;
        #pragma unroll
        for (int k = 0; k < D; ++k)
            acc = fmaf(rows[r][k], Wt[k * 65 + j], acc);
        // jax.nn.elu: x>0 ? x : expm1(x)
        t[gr * D + j] = (acc > 0.f) ? acc : expm1f(acc);
    }
}

// ---------------------------------------------------------------------------
// SpMM: h[r][:] = sum_{e in row r} val[e] * t[col[e]][:]
// One wave per row (lane = dim). No atomics (CSR segments are contiguous).
// Also accumulates into out: store on first head, += after.
// ---------------------------------------------------------------------------
__global__ __launch_bounds__(256) void spmm_kernel(
        const float* __restrict__ t,
        const int*   __restrict__ edge_col,
        const float* __restrict__ edge_val,
        const int*   __restrict__ row_ptr,
        float* __restrict__ h,
        float* __restrict__ out,
        int first_head) {
    const int lane = threadIdx.x & 63;
    const int row  = (blockIdx.x * blockDim.x + threadIdx.x) >> 6;
    if (row >= N_NODES) return;

    const int e0 = row_ptr[row];
    const int e1 = row_ptr[row + 1];
    float acc = 0.f;
    for (int e = e0; e < e1; ++e) {
        const float v = edge_val[e];
        const int   c = edge_col[e];
        acc = fmaf(v, t[c * D + lane], acc);
    }
    h[row * D + lane] = acc;
    if (first_head) out[row * D + lane] = acc;
    else            out[row * D + lane] += acc;
}

// ---------------------------------------------------------------------------
extern "C" void kernel_launch(void* const* d_in, const int* in_sizes, int n_in,
                              void* d_out, int out_size, void* d_ws, size_t ws_size,
                              hipStream_t stream) {
    const float* x        = (const float*)d_in[0];  // [N, 64]
    const float* edge_val = (const float*)d_in[1];  // [E]
    const float* W        = (const float*)d_in[2];  // [4, 64, 64]
    const float* b        = (const float*)d_in[3];  // [4, 64]
    // d_in[4] = edge_row (sorted), d_in[5] = edge_col
    const int* edge_row   = (const int*)d_in[4];
    const int* edge_col   = (const int*)d_in[5];
    const int* event_type = (const int*)d_in[6];    // [N] (int32 on device)
    float* out = (float*)d_out;

    float* t       = (float*)d_ws;                  // [N*64]
    float* h       = t + (size_t)N_NODES * D;       // [N*64]
    int*   row_ptr = (int*)(h + (size_t)N_NODES * D); // [N+1]

    rowptr_kernel<<<(N_NODES + 256) / 256, 256, 0, stream>>>(edge_row, row_ptr);

    const float* cur = x;
    for (int i = 0; i < N_HEAD; ++i) {
        linear_elu_kernel<<<(N_NODES + L_ROWS - 1) / L_ROWS, 256, 0, stream>>>(
            cur, W + (size_t)i * D * D, b + (size_t)i * D,
            (i == 0) ? event_type : nullptr, t);
        spmm_kernel<<<(N_NODES * 64 + 255) / 256, 256, 0, stream>>>(
            t, edge_col, edge_val, row_ptr, h, out, (i == 0) ? 1 : 0);
        cur = h;
    }
}

// Round 2
// 227.905 us; speedup vs baseline: 1.9708x; 1.9708x over previous
//
#include <hip/hip_runtime.h>
#include <math.h>

#define N_NODES 50000
#define D       64
#define N_EDGES 800000
#define N_HEAD  4

// ---------------------------------------------------------------------------
// row_ptr[r] = lower_bound(edge_row, r)  for r in [0, N_NODES], edge_row sorted
// ---------------------------------------------------------------------------
__global__ void rowptr_kernel(const int* __restrict__ edge_row,
                              int* __restrict__ row_ptr) {
    int r = blockIdx.x * blockDim.x + threadIdx.x;
    if (r > N_NODES) return;
    int lo = 0, hi = N_EDGES;
    while (lo < hi) {
        int mid = (lo + hi) >> 1;
        if (edge_row[mid] < r) lo = mid + 1; else hi = mid;
    }
    row_ptr[r] = lo;
}

// ---------------------------------------------------------------------------
// t[n][j] = elu( sum_k in[n][k] * W[j][k] + b[j] )
// lane j holds W[j][0..63] in 64 VGPRs; row data comes in as wave-uniform
// scalar loads (readfirstlane'd row index). No LDS at all.
// ---------------------------------------------------------------------------
__global__ __launch_bounds__(256) void linear_elu_kernel(
        const float* __restrict__ in,
        const float* __restrict__ W,   // [64][64] row-major, W[j][k]
        const float* __restrict__ b,   // [64]
        const int*  __restrict__ et,   // mask if et[n]==0 (head 0 only)
        float* __restrict__ t,
        int head0) {
    const int lane = threadIdx.x & 63;
    const int wid  = (blockIdx.x * blockDim.x + threadIdx.x) >> 6;
    const int nwav = (gridDim.x * blockDim.x) >> 6;

    // W[lane][*] into registers via float4 loads
    float4 w4[16];
    {
        const float4* wp = (const float4*)(W + lane * D);
        #pragma unroll
        for (int i = 0; i < 16; ++i) w4[i] = wp[i];
    }
    const float* w = (const float*)w4;
    const float bj = b[lane];

    for (int row0 = wid; row0 < N_NODES; row0 += nwav) {
        const int row = __builtin_amdgcn_readfirstlane(row0);
        float acc = bj;
        if (!(head0 && et[row] == 0)) {
            const float* rp = in + (size_t)row * D;
            #pragma unroll
            for (int k = 0; k < D; ++k)
                acc = fmaf(rp[k], w[k], acc);
        }
        // jax.nn.elu: x>0 ? x : expm1(x)
        t[(size_t)row * D + lane] = (acc > 0.f) ? acc : expm1f(acc);
    }
}

// ---------------------------------------------------------------------------
// SpMM: h[r][:] = sum_{e in row r} val[e] * t[col[e]][:]
// One wave per row (lane = dim). Edge loop unrolled 8-deep so 8 gathers are
// in flight concurrently (the previous version had MLP=1 -> latency-bound).
// ---------------------------------------------------------------------------
__global__ __launch_bounds__(256) void spmm_kernel(
        const float* __restrict__ t,
        const int*   __restrict__ edge_col,
        const float* __restrict__ edge_val,
        const int*   __restrict__ row_ptr,
        float* __restrict__ h,
        float* __restrict__ out,
        int first_head, int write_h) {
    const int lane = threadIdx.x & 63;
    int row0 = (blockIdx.x * blockDim.x + threadIdx.x) >> 6;
    if (row0 >= N_NODES) return;
    const int row = __builtin_amdgcn_readfirstlane(row0);

    const int e0 = row_ptr[row];
    const int e1 = row_ptr[row + 1];
    float acc = 0.f;
    int e = e0;

    for (; e + 8 <= e1; e += 8) {
        int   c[8];
        float v[8];
        #pragma unroll
        for (int u = 0; u < 8; ++u) { c[u] = edge_col[e + u]; v[u] = edge_val[e + u]; }
        float g[8];
        #pragma unroll
        for (int u = 0; u < 8; ++u) g[u] = t[(size_t)c[u] * D + lane];
        #pragma unroll
        for (int u = 0; u < 8; ++u) acc = fmaf(v[u], g[u], acc);
    }
    if (e + 4 <= e1) {
        int   c[4];
        float v[4];
        #pragma unroll
        for (int u = 0; u < 4; ++u) { c[u] = edge_col[e + u]; v[u] = edge_val[e + u]; }
        float g[4];
        #pragma unroll
        for (int u = 0; u < 4; ++u) g[u] = t[(size_t)c[u] * D + lane];
        #pragma unroll
        for (int u = 0; u < 4; ++u) acc = fmaf(v[u], g[u], acc);
        e += 4;
    }
    for (; e < e1; ++e)
        acc = fmaf(edge_val[e], t[(size_t)edge_col[e] * D + lane], acc);

    if (write_h)    h[(size_t)row * D + lane] = acc;
    if (first_head) out[(size_t)row * D + lane] = acc;
    else            out[(size_t)row * D + lane] += acc;
}

// ---------------------------------------------------------------------------
extern "C" void kernel_launch(void* const* d_in, const int* in_sizes, int n_in,
                              void* d_out, int out_size, void* d_ws, size_t ws_size,
                              hipStream_t stream) {
    const float* x        = (const float*)d_in[0];  // [N, 64]
    const float* edge_val = (const float*)d_in[1];  // [E]
    const float* W        = (const float*)d_in[2];  // [4, 64, 64]
    const float* b        = (const float*)d_in[3];  // [4, 64]
    const int* edge_row   = (const int*)d_in[4];    // sorted
    const int* edge_col   = (const int*)d_in[5];
    const int* event_type = (const int*)d_in[6];    // [N] (int32 on device)
    float* out = (float*)d_out;

    float* t       = (float*)d_ws;                    // [N*64]
    float* h       = t + (size_t)N_NODES * D;         // [N*64]
    int*   row_ptr = (int*)(h + (size_t)N_NODES * D); // [N+1]

    rowptr_kernel<<<(N_NODES + 256) / 256, 256, 0, stream>>>(edge_row, row_ptr);

    const float* cur = x;
    for (int i = 0; i < N_HEAD; ++i) {
        linear_elu_kernel<<<1024, 256, 0, stream>>>(
            cur, W + (size_t)i * D * D, b + (size_t)i * D,
            event_type, t, (i == 0) ? 1 : 0);
        spmm_kernel<<<(N_NODES * 64 + 255) / 256, 256, 0, stream>>>(
            t, edge_col, edge_val, row_ptr, h, out,
            (i == 0) ? 1 : 0, (i < N_HEAD - 1) ? 1 : 0);
        cur = h;
    }
}